// Round 9
// baseline (1008.706 us; speedup 1.0000x reference)
//
#include <hip/hip_runtime.h>
#include <cfloat>

#define D 64
#define K 512
#define MARGIN 4e-4f
#define WL_CAP 262144

typedef __attribute__((ext_vector_type(8))) short bf16x8;
typedef __attribute__((ext_vector_type(4))) float f32x4;

__device__ __forceinline__ short f2bf(float x) {          // fp32 -> bf16 RNE
    unsigned u = __float_as_uint(x);
    u += 0x7fffu + ((u >> 16) & 1u);
    return (short)(u >> 16);
}
__device__ __forceinline__ float bf2f(short s) {
    return __uint_as_float(((unsigned)(unsigned short)s) << 16);
}

__device__ __forceinline__ void gload_lds16(const void* g, void* l) {
    __builtin_amdgcn_global_load_lds(
        (const __attribute__((address_space(1))) unsigned int*)g,
        (__attribute__((address_space(3))) unsigned int*)l, 16, 0, 0);
}

// ===========================================================================
// numpy-bit-exact helpers (VERIFIED bit-match R3-R8: absmax 0.0)
// ===========================================================================
__device__ __forceinline__ float np_pairwise64_sq(const float* a) {
    float r[8];
    #pragma unroll
    for (int j = 0; j < 8; ++j) r[j] = __fmul_rn(a[j], a[j]);
    #pragma unroll
    for (int i = 8; i < 64; i += 8) {
        #pragma unroll
        for (int j = 0; j < 8; ++j)
            r[j] = __fadd_rn(r[j], __fmul_rn(a[i + j], a[i + j]));
    }
    return __fadd_rn(__fadd_rn(__fadd_rn(r[0], r[1]), __fadd_rn(r[2], r[3])),
                     __fadd_rn(__fadd_rn(r[4], r[5]), __fadd_rn(r[6], r[7])));
}

__device__ __forceinline__ float np_seqfma_dot64(const float* x, const float* y) {
    float acc = 0.f;
    #pragma unroll
    for (int d = 0; d < 64; ++d) acc = __fmaf_rn(x[d], y[d], acc);
    return acc;
}

// ===========================================================================
// Kernel P: one-time prep. All 32 blocks: bf16 hi/lo split of E in
// MFMA-fragment order ehl[ch][ct][p][lane][8]. Blocks 0-1 additionally
// compute np-exact ee[k]; block 0 thread 0 zeroes the worklist counter.
// ===========================================================================
__global__ void vq_prep_kernel(const float* __restrict__ emb, short* __restrict__ ehl,
                               float* __restrict__ ee, int* __restrict__ wl_cnt) {
    const int t = threadIdx.x, b = blockIdx.x;
    if (b == 0 && t == 0) *wl_cnt = 0;

    const int gid = b * 256 + t;                      // 8192 frag jobs
    const int l  = gid & 63;
    const int p  = (gid >> 6) & 3;
    const int code = ((gid >> 11) << 7) + (((gid >> 8) & 7) << 4) + (l & 15);
    const int d0 = ((p & 1) << 5) + ((l >> 4) << 3);
    const float4 v0 = *(const float4*)(emb + code * D + d0);
    const float4 v1 = *(const float4*)(emb + code * D + d0 + 4);
    const float f[8] = {v0.x, v0.y, v0.z, v0.w, v1.x, v1.y, v1.z, v1.w};
    bf16x8 o;
    #pragma unroll
    for (int j = 0; j < 8; ++j) {
        const short h = f2bf(f[j]);
        o[j] = (p < 2) ? h : f2bf(f[j] - bf2f(h));
    }
    *(bf16x8*)(ehl + (long long)gid * 8) = o;

    if (b < 2) {                                      // ee jobs: k = 0..511
        const int k = b * 256 + t;
        float e[64];
        const float4* e4 = reinterpret_cast<const float4*>(emb) + k * 16;
        #pragma unroll
        for (int j = 0; j < 16; ++j) {
            float4 tt = e4[j];
            e[4*j] = tt.x; e[4*j+1] = tt.y; e[4*j+2] = tt.z; e[4*j+3] = tt.w;
        }
        ee[k] = np_pairwise64_sq(e);
    }
}

// ===========================================================================
// Kernel A (fused): MFMA score + direct z_q write. 256 thr = 4 waves,
// T=8 A-tiles/wave (128 rows/wave, 512 rows/block), double-buffered 32KB
// B-chunks. Fast-path score: G = zh.eh + zh.el + zl.eh (same split as
// verified R5-R8); proxy = bits(score+0.5) with code packed in the 9
// mantissa LSBs -> umin tracks (argmin, tie-break-low) in ONE reg.
// Quantization error <= 511 ulp(~0.5) = 6.1e-5, covered by MARGIN=4e-4
// (needed: 2*(1.2e-5 split + 6.1e-5 quant) + 6.1e-5 ref-noise = 2.07e-4).
// Rows with proxy-gap < MARGIN go to the exact refine via worklist.
// Epilogue writes out[row] = emb[best] for BOTH tuple outputs (gather fused).
// ===========================================================================
__global__ __launch_bounds__(256, 2) void vq_score_fused_kernel(
    const float* __restrict__ z, const short* __restrict__ ehl,
    const float* __restrict__ ee, const float* __restrict__ emb,
    float* __restrict__ out, int* __restrict__ wl, int* __restrict__ wl_cnt,
    long long nRows)
{
    __shared__ short eB[2][16384];    // 2 x 32 KB double buffer
    __shared__ float eeL[512];

    const int t  = threadIdx.x;
    const int l  = t & 63;
    const int w  = t >> 6;            // wave 0..3
    const int kg = l >> 4;
    const int cl = l & 15;

    const long long blockRow = (long long)blockIdx.x * 512;
    const long long wrow = blockRow + w * 128;

    // ---- stage chunk 0 (async; latency hidden under A-fragment build)
    {
        const short* src = ehl + w * 4096 + l * 8;
        short* dst = &eB[0][w * 4096 + l * 8];
        #pragma unroll
        for (int i = 0; i < 8; ++i)
            gload_lds16(src + i * 512, dst + i * 512);
    }
    eeL[t] = ee[t];
    eeL[t + 256] = ee[t + 256];

    // ---- A fragments: 8 tiles x (hi d0-31, hi d32-63, lo d0-31, lo d32-63)
    bf16x8 aH0[8], aH1[8], aL0[8], aL1[8];
    #pragma unroll
    for (int a = 0; a < 8; ++a) {
        const float* zr = z + (wrow + a * 16 + cl) * D;
        const float4 v0 = *(const float4*)(zr + kg * 8);
        const float4 v1 = *(const float4*)(zr + kg * 8 + 4);
        const float4 v2 = *(const float4*)(zr + 32 + kg * 8);
        const float4 v3 = *(const float4*)(zr + 32 + kg * 8 + 4);
        const float d0[8] = {v0.x,v0.y,v0.z,v0.w,v1.x,v1.y,v1.z,v1.w};
        const float d1[8] = {v2.x,v2.y,v2.z,v2.w,v3.x,v3.y,v3.z,v3.w};
        #pragma unroll
        for (int i = 0; i < 8; ++i) {
            const short h = f2bf(d0[i]); aH0[a][i] = h; aL0[a][i] = f2bf(d0[i] - bf2f(h));
            const short g = f2bf(d1[i]); aH1[a][i] = g; aL1[a][i] = f2bf(d1[i] - bf2f(g));
        }
    }

    unsigned m1p[8][4], m2p[8][4];
    #pragma unroll
    for (int a = 0; a < 8; ++a)
        #pragma unroll
        for (int r = 0; r < 4; ++r) { m1p[a][r] = 0x7f800000u; m2p[a][r] = 0x7f800000u; }

    __syncthreads();                  // chunk-0 staging + eeL drained

    for (int ch = 0; ch < 4; ++ch) {
        if (ch < 3) {                 // async stage of next chunk -> other buf
            const short* src = ehl + (ch + 1) * 16384 + w * 4096 + l * 8;
            short* dst = &eB[(ch + 1) & 1][w * 4096 + l * 8];
            #pragma unroll
            for (int i = 0; i < 8; ++i)
                gload_lds16(src + i * 512, dst + i * 512);
        }

        const short* lb = eB[ch & 1];
        #pragma unroll
        for (int ct = 0; ct < 8; ++ct) {
            const short* fb = lb + ct * 2048 + l * 8;
            const bf16x8 b0 = *(const bf16x8*)(fb);
            const bf16x8 b1 = *(const bf16x8*)(fb + 512);
            const bf16x8 b2 = *(const bf16x8*)(fb + 1024);
            const bf16x8 b3 = *(const bf16x8*)(fb + 1536);

            const float ek05 = eeL[ch * 128 + ct * 16 + cl] + 0.5f;
            const unsigned code = (unsigned)((ch * 128 + ct * 16) | cl);

            // two groups of 4 tiles: 4 independent MFMA chains each,
            // group-0 epilogue VALU overlaps group-1 MFMAs
            #pragma unroll
            for (int g2 = 0; g2 < 2; ++g2) {
                f32x4 acc[4];
                #pragma unroll
                for (int a = 0; a < 4; ++a) acc[a] = f32x4{0.f, 0.f, 0.f, 0.f};
                #pragma unroll
                for (int a = 0; a < 4; ++a) acc[a] = __builtin_amdgcn_mfma_f32_16x16x32_bf16(aH0[g2*4+a], b0, acc[a], 0, 0, 0);
                #pragma unroll
                for (int a = 0; a < 4; ++a) acc[a] = __builtin_amdgcn_mfma_f32_16x16x32_bf16(aH1[g2*4+a], b1, acc[a], 0, 0, 0);
                #pragma unroll
                for (int a = 0; a < 4; ++a) acc[a] = __builtin_amdgcn_mfma_f32_16x16x32_bf16(aH0[g2*4+a], b2, acc[a], 0, 0, 0);
                #pragma unroll
                for (int a = 0; a < 4; ++a) acc[a] = __builtin_amdgcn_mfma_f32_16x16x32_bf16(aH1[g2*4+a], b3, acc[a], 0, 0, 0);
                #pragma unroll
                for (int a = 0; a < 4; ++a) acc[a] = __builtin_amdgcn_mfma_f32_16x16x32_bf16(aL0[g2*4+a], b0, acc[a], 0, 0, 0);
                #pragma unroll
                for (int a = 0; a < 4; ++a) acc[a] = __builtin_amdgcn_mfma_f32_16x16x32_bf16(aL1[g2*4+a], b1, acc[a], 0, 0, 0);

                #pragma unroll
                for (int a = 0; a < 4; ++a) {
                    #pragma unroll
                    for (int r = 0; r < 4; ++r) {
                        const float s = __fmaf_rn(-2.0f, acc[a][r], ek05);   // >0 always
                        const unsigned p = (__float_as_uint(s) & 0xfffffe00u) | code;
                        const int ai = g2 * 4 + a;
                        m2p[ai][r] = min(m2p[ai][r], max(m1p[ai][r], p));
                        m1p[ai][r] = min(m1p[ai][r], p);
                    }
                }
            }
        }
        __syncthreads();   // drains async stage; WAR before buf overwrite
    }

    // merge (m1p,m2p) across the 16 cl-lanes of each kg group (packed:
    // code embedded -> umin keeps lowest-index on quantized ties)
    #pragma unroll
    for (int a = 0; a < 8; ++a) {
        #pragma unroll
        for (int r = 0; r < 4; ++r) {
            #pragma unroll
            for (int off = 1; off < 16; off <<= 1) {
                const unsigned o1 = (unsigned)__shfl_xor((int)m1p[a][r], off);
                const unsigned o2 = (unsigned)__shfl_xor((int)m2p[a][r], off);
                const unsigned lo = min(m1p[a][r], o1);
                const unsigned hi = max(m1p[a][r], o1);
                m2p[a][r] = min(min(m2p[a][r], o2), hi);
                m1p[a][r] = lo;
            }
        }
    }

    // best-code per row -> LDS; flagged rows -> worklist
    int* bestL = (int*)&eB[0][0];     // 512 ints (eB reads are done)
    if (cl == 0) {
        #pragma unroll
        for (int a = 0; a < 8; ++a)
            #pragma unroll
            for (int r = 0; r < 4; ++r) {
                const int rowLocal = w * 128 + a * 16 + kg * 4 + r;   // D-row map (HW-verified)
                bestL[rowLocal] = (int)(m1p[a][r] & 511u);
                const float f1 = __uint_as_float(m1p[a][r] & 0xfffffe00u);
                const float f2 = __uint_as_float(m2p[a][r] & 0xfffffe00u);
                if (f2 - f1 < MARGIN) {
                    const int pos = atomicAdd(wl_cnt, 1);
                    if (pos < WL_CAP) wl[pos] = (int)(blockRow + rowLocal);
                }
            }
    }
    __syncthreads();

    // fused gather: write both tuple outputs, coalesced float4
    const float4* emb4 = reinterpret_cast<const float4*>(emb);
    float4* out4 = reinterpret_cast<float4*>(out);
    const long long total4 = nRows * 16;
    #pragma unroll
    for (int i = 0; i < 32; ++i) {
        const int c2 = t + i * 256;               // 0..8191: 512 rows x 16 f4
        const int rowLocal = c2 >> 4;
        const int q = c2 & 15;
        const int codeB = bestL[rowLocal];
        const float4 v = emb4[codeB * 16 + q];
        const long long o = (blockRow + rowLocal) * 16 + q;
        out4[o] = v;
        out4[o + total4] = v;
    }
}

// ===========================================================================
// Kernel C: numpy-bit-exact re-resolution of flagged rows; writes out
// directly (both copies). launch_bounds(256,1): za/eb stay in registers.
// ===========================================================================
__global__ __launch_bounds__(256, 1) void vq_refine_np_kernel(
    const float* __restrict__ z, const float* __restrict__ emb,
    const float* __restrict__ ee, const int* __restrict__ wl,
    const int* __restrict__ wl_cnt, float* __restrict__ out, long long nRows)
{
    const int lane = threadIdx.x & 63;
    const int wid  = blockIdx.x * 4 + (threadIdx.x >> 6);
    const int nW   = gridDim.x * 4;
    const int cnt  = min(*wl_cnt, WL_CAP);
    const long long totalF = nRows * 64;

    for (int i = wid; i < cnt; i += nW) {
        const long long r = wl[i];

        float za[64];
        const float4* z4 = reinterpret_cast<const float4*>(z + r * D);
        #pragma unroll
        for (int j = 0; j < 16; ++j) {
            float4 tt = z4[j];
            za[4*j] = tt.x; za[4*j+1] = tt.y; za[4*j+2] = tt.z; za[4*j+3] = tt.w;
        }
        const float zz = np_pairwise64_sq(za);

        float best = FLT_MAX; int bk = 0x7fffffff;
        for (int i8 = 0; i8 < 8; ++i8) {
            const int k = (i8 << 6) + lane;          // ascending per lane
            float eb[64];
            const float4* e4 = reinterpret_cast<const float4*>(emb) + k * 16;
            #pragma unroll
            for (int j = 0; j < 16; ++j) {
                float4 tt = e4[j];
                eb[4*j] = tt.x; eb[4*j+1] = tt.y; eb[4*j+2] = tt.z; eb[4*j+3] = tt.w;
            }
            const float G = np_seqfma_dot64(za, eb);
            const float dist = __fadd_rn(__fsub_rn(zz, __fmul_rn(2.0f, G)), ee[k]);
            if (dist < best) { best = dist; bk = k; }
        }
        // cross-lane min, lowest-k tie-break (== numpy first-min)
        #pragma unroll
        for (int off = 32; off; off >>= 1) {
            const float ob = __shfl_xor(best, off);
            const int   ok = __shfl_xor(bk, off);
            if (ob < best || (ob == best && ok < bk)) { best = ob; bk = ok; }
        }
        // patch both output copies (256B each, 1 float/lane)
        const float v = emb[bk * D + lane];
        out[r * D + lane] = v;
        out[totalF + r * D + lane] = v;
    }
}

// ===========================================================================
extern "C" void kernel_launch(void* const* d_in, const int* in_sizes, int n_in,
                              void* d_out, int out_size, void* d_ws, size_t ws_size,
                              hipStream_t stream) {
    const float* z   = (const float*)d_in[0];   // [N, 64] fp32
    const float* emb = (const float*)d_in[1];   // [512, 64] fp32
    float* out = (float*)d_out;                 // 2 x [N, 64] fp32

    const long long nRows = (long long)in_sizes[0] / D;       // 524288

    char* p = (char*)d_ws;
    float* ee     = (float*)p;                        // 2 KB
    short* ehl    = (short*)(p + 4096);               // 128 KB
    int*   wl_cnt = (int*)(p + 4096 + 131072);        // 4 B (pad to 256)
    int*   wl     = (int*)(p + 4096 + 131072 + 256);  // 1 MB

    vq_prep_kernel<<<32, 256, 0, stream>>>(emb, ehl, ee, wl_cnt);

    const int scoreBlocks = (int)(nRows / 512);               // 1024
    vq_score_fused_kernel<<<scoreBlocks, 256, 0, stream>>>(
        z, ehl, ee, emb, out, wl, wl_cnt, nRows);

    vq_refine_np_kernel<<<512, 256, 0, stream>>>(z, emb, ee, wl, wl_cnt, out, nRows);
}

// Round 10
// 637.560 us; speedup vs baseline: 1.5821x; 1.5821x over previous
//
#include <hip/hip_runtime.h>
#include <cfloat>

#define D 64
#define K 512
#define MARGIN 4e-4f
#define WL_CAP 262144

typedef __attribute__((ext_vector_type(8))) short bf16x8;
typedef __attribute__((ext_vector_type(4))) float f32x4;

__device__ __forceinline__ short f2bf(float x) {          // fp32 -> bf16 RNE
    unsigned u = __float_as_uint(x);
    u += 0x7fffu + ((u >> 16) & 1u);
    return (short)(u >> 16);
}
__device__ __forceinline__ float bf2f(short s) {
    return __uint_as_float(((unsigned)(unsigned short)s) << 16);
}

__device__ __forceinline__ void gload_lds16(const void* g, void* l) {
    __builtin_amdgcn_global_load_lds(
        (const __attribute__((address_space(1))) unsigned int*)g,
        (__attribute__((address_space(3))) unsigned int*)l, 16, 0, 0);
}

// ===========================================================================
// numpy-bit-exact helpers (VERIFIED bit-match R3-R9: absmax 0.0)
// ===========================================================================
__device__ __forceinline__ float np_pairwise64_sq(const float* a) {
    float r[8];
    #pragma unroll
    for (int j = 0; j < 8; ++j) r[j] = __fmul_rn(a[j], a[j]);
    #pragma unroll
    for (int i = 8; i < 64; i += 8) {
        #pragma unroll
        for (int j = 0; j < 8; ++j)
            r[j] = __fadd_rn(r[j], __fmul_rn(a[i + j], a[i + j]));
    }
    return __fadd_rn(__fadd_rn(__fadd_rn(r[0], r[1]), __fadd_rn(r[2], r[3])),
                     __fadd_rn(__fadd_rn(r[4], r[5]), __fadd_rn(r[6], r[7])));
}

__device__ __forceinline__ float np_seqfma_dot64(const float* x, const float* y) {
    float acc = 0.f;
    #pragma unroll
    for (int d = 0; d < 64; ++d) acc = __fmaf_rn(x[d], y[d], acc);
    return acc;
}

// ===========================================================================
// Kernel P: one-time prep (bf16 hi/lo fragment split + np-exact ee + wl_cnt=0)
// ===========================================================================
__global__ void vq_prep_kernel(const float* __restrict__ emb, short* __restrict__ ehl,
                               float* __restrict__ ee, int* __restrict__ wl_cnt) {
    const int t = threadIdx.x, b = blockIdx.x;
    if (b == 0 && t == 0) *wl_cnt = 0;

    const int gid = b * 256 + t;                      // 8192 frag jobs
    const int l  = gid & 63;
    const int p  = (gid >> 6) & 3;
    const int code = ((gid >> 11) << 7) + (((gid >> 8) & 7) << 4) + (l & 15);
    const int d0 = ((p & 1) << 5) + ((l >> 4) << 3);
    const float4 v0 = *(const float4*)(emb + code * D + d0);
    const float4 v1 = *(const float4*)(emb + code * D + d0 + 4);
    const float f[8] = {v0.x, v0.y, v0.z, v0.w, v1.x, v1.y, v1.z, v1.w};
    bf16x8 o;
    #pragma unroll
    for (int j = 0; j < 8; ++j) {
        const short h = f2bf(f[j]);
        o[j] = (p < 2) ? h : f2bf(f[j] - bf2f(h));
    }
    *(bf16x8*)(ehl + (long long)gid * 8) = o;

    if (b < 2) {                                      // ee jobs: k = 0..511
        const int k = b * 256 + t;
        float e[64];
        const float4* e4 = reinterpret_cast<const float4*>(emb) + k * 16;
        #pragma unroll
        for (int j = 0; j < 16; ++j) {
            float4 tt = e4[j];
            e[4*j] = tt.x; e[4*j+1] = tt.y; e[4*j+2] = tt.z; e[4*j+3] = tt.w;
        }
        ee[k] = np_pairwise64_sq(e);
    }
}

// ===========================================================================
// Kernel A (fused, T=2): MFMA score + direct z_q write.
// 256 thr = 4 waves; wave owns 32 rows (2 A-tiles); block = 128 rows.
// Codes processed in 8 half-chunks of 64 codes, double-buffered 2x16KB ->
// LDS 34.8KB -> 4 blocks/CU = 16 waves/CU (4/SIMD), regs ~90 <= 128 cap.
// Fast path identical numerics to R9 PASS: G = zh.eh+zh.el+zl.eh; packed
// proxy bits(score+0.5)|code (9 LSB) -> umin = argmin + tie-break-low.
// Margin 4e-4 >= 1.9x worst-case fast-vs-ref divergence (see R9 analysis).
// ===========================================================================
__global__ __launch_bounds__(256, 4) void vq_score_fused_kernel(
    const float* __restrict__ z, const short* __restrict__ ehl,
    const float* __restrict__ ee, const float* __restrict__ emb,
    float* __restrict__ out, int* __restrict__ wl, int* __restrict__ wl_cnt,
    long long nRows)
{
    __shared__ short eB[2][8192];     // 2 x 16 KB double buffer (64 codes)
    __shared__ float eeL[512];

    const int t  = threadIdx.x;
    const int l  = t & 63;
    const int w  = t >> 6;            // wave 0..3
    const int kg = l >> 4;
    const int cl = l & 15;

    const long long blockRow = (long long)blockIdx.x * 128;
    const long long wrow = blockRow + w * 32;

    // ---- stage half-chunk 0 (async; hidden under A-fragment build)
    {
        const short* src = ehl + t * 8;
        short* dst = &eB[0][t * 8];
        #pragma unroll
        for (int i = 0; i < 4; ++i)
            gload_lds16(src + i * 2048, dst + i * 2048);
    }
    eeL[t] = ee[t];
    eeL[t + 256] = ee[t + 256];

    // ---- A fragments: 2 tiles x (hi d0-31, hi d32-63, lo d0-31, lo d32-63)
    bf16x8 aH0[2], aH1[2], aL0[2], aL1[2];
    #pragma unroll
    for (int a = 0; a < 2; ++a) {
        const float* zr = z + (wrow + a * 16 + cl) * D;
        const float4 v0 = *(const float4*)(zr + kg * 8);
        const float4 v1 = *(const float4*)(zr + kg * 8 + 4);
        const float4 v2 = *(const float4*)(zr + 32 + kg * 8);
        const float4 v3 = *(const float4*)(zr + 32 + kg * 8 + 4);
        const float d0[8] = {v0.x,v0.y,v0.z,v0.w,v1.x,v1.y,v1.z,v1.w};
        const float d1[8] = {v2.x,v2.y,v2.z,v2.w,v3.x,v3.y,v3.z,v3.w};
        #pragma unroll
        for (int i = 0; i < 8; ++i) {
            const short h = f2bf(d0[i]); aH0[a][i] = h; aL0[a][i] = f2bf(d0[i] - bf2f(h));
            const short g = f2bf(d1[i]); aH1[a][i] = g; aL1[a][i] = f2bf(d1[i] - bf2f(g));
        }
    }

    unsigned m1p[2][4], m2p[2][4];
    #pragma unroll
    for (int a = 0; a < 2; ++a)
        #pragma unroll
        for (int r = 0; r < 4; ++r) { m1p[a][r] = 0x7f800000u; m2p[a][r] = 0x7f800000u; }

    __syncthreads();                  // chunk-0 staging + eeL drained

    for (int hc = 0; hc < 8; ++hc) {
        if (hc < 7) {                 // async stage of next half-chunk
            const short* src = ehl + (hc + 1) * 8192 + t * 8;
            short* dst = &eB[(hc + 1) & 1][t * 8];
            #pragma unroll
            for (int i = 0; i < 4; ++i)
                gload_lds16(src + i * 2048, dst + i * 2048);
        }

        const short* lb = eB[hc & 1];
        #pragma unroll
        for (int ct = 0; ct < 4; ++ct) {
            const short* fb = lb + ct * 2048 + l * 8;
            const bf16x8 b0 = *(const bf16x8*)(fb);
            const bf16x8 b1 = *(const bf16x8*)(fb + 512);
            const bf16x8 b2 = *(const bf16x8*)(fb + 1024);
            const bf16x8 b3 = *(const bf16x8*)(fb + 1536);

            f32x4 acc0 = {0.f, 0.f, 0.f, 0.f};
            f32x4 acc1 = {0.f, 0.f, 0.f, 0.f};
            acc0 = __builtin_amdgcn_mfma_f32_16x16x32_bf16(aH0[0], b0, acc0, 0, 0, 0);
            acc1 = __builtin_amdgcn_mfma_f32_16x16x32_bf16(aH0[1], b0, acc1, 0, 0, 0);
            acc0 = __builtin_amdgcn_mfma_f32_16x16x32_bf16(aH1[0], b1, acc0, 0, 0, 0);
            acc1 = __builtin_amdgcn_mfma_f32_16x16x32_bf16(aH1[1], b1, acc1, 0, 0, 0);
            acc0 = __builtin_amdgcn_mfma_f32_16x16x32_bf16(aH0[0], b2, acc0, 0, 0, 0);
            acc1 = __builtin_amdgcn_mfma_f32_16x16x32_bf16(aH0[1], b2, acc1, 0, 0, 0);
            acc0 = __builtin_amdgcn_mfma_f32_16x16x32_bf16(aH1[0], b3, acc0, 0, 0, 0);
            acc1 = __builtin_amdgcn_mfma_f32_16x16x32_bf16(aH1[1], b3, acc1, 0, 0, 0);
            acc0 = __builtin_amdgcn_mfma_f32_16x16x32_bf16(aL0[0], b0, acc0, 0, 0, 0);
            acc1 = __builtin_amdgcn_mfma_f32_16x16x32_bf16(aL0[1], b0, acc1, 0, 0, 0);
            acc0 = __builtin_amdgcn_mfma_f32_16x16x32_bf16(aL1[0], b1, acc0, 0, 0, 0);
            acc1 = __builtin_amdgcn_mfma_f32_16x16x32_bf16(aL1[1], b1, acc1, 0, 0, 0);

            const float ek05 = eeL[hc * 64 + ct * 16 + cl] + 0.5f;
            const unsigned code = (unsigned)((hc * 64 + ct * 16) | cl);
            #pragma unroll
            for (int r = 0; r < 4; ++r) {
                const float s0 = __fmaf_rn(-2.0f, acc0[r], ek05);   // > 0 always
                const unsigned p0 = (__float_as_uint(s0) & 0xfffffe00u) | code;
                m2p[0][r] = min(m2p[0][r], max(m1p[0][r], p0));
                m1p[0][r] = min(m1p[0][r], p0);
                const float s1 = __fmaf_rn(-2.0f, acc1[r], ek05);
                const unsigned p1 = (__float_as_uint(s1) & 0xfffffe00u) | code;
                m2p[1][r] = min(m2p[1][r], max(m1p[1][r], p1));
                m1p[1][r] = min(m1p[1][r], p1);
            }
        }
        __syncthreads();   // drains async stage; WAR before buf overwrite
    }

    // merge (m1p,m2p) across the 16 cl-lanes of each kg group
    #pragma unroll
    for (int a = 0; a < 2; ++a) {
        #pragma unroll
        for (int r = 0; r < 4; ++r) {
            #pragma unroll
            for (int off = 1; off < 16; off <<= 1) {
                const unsigned o1 = (unsigned)__shfl_xor((int)m1p[a][r], off);
                const unsigned o2 = (unsigned)__shfl_xor((int)m2p[a][r], off);
                const unsigned lo = min(m1p[a][r], o1);
                const unsigned hi = max(m1p[a][r], o1);
                m2p[a][r] = min(min(m2p[a][r], o2), hi);
                m1p[a][r] = lo;
            }
        }
    }

    // best-code per row -> LDS; flagged rows -> worklist
    int* bestL = (int*)&eB[0][0];     // 128 ints (eB[0] reads done)
    if (cl == 0) {
        #pragma unroll
        for (int a = 0; a < 2; ++a)
            #pragma unroll
            for (int r = 0; r < 4; ++r) {
                const int rowLocal = w * 32 + a * 16 + kg * 4 + r;   // D-row map (HW-verified)
                bestL[rowLocal] = (int)(m1p[a][r] & 511u);
                const float f1 = __uint_as_float(m1p[a][r] & 0xfffffe00u);
                const float f2 = __uint_as_float(m2p[a][r] & 0xfffffe00u);
                if (f2 - f1 < MARGIN) {
                    const int pos = atomicAdd(wl_cnt, 1);
                    if (pos < WL_CAP) wl[pos] = (int)(blockRow + rowLocal);
                }
            }
    }
    __syncthreads();

    // fused gather: write both tuple outputs, coalesced float4
    const float4* emb4 = reinterpret_cast<const float4*>(emb);
    float4* out4 = reinterpret_cast<float4*>(out);
    const long long total4 = nRows * 16;
    #pragma unroll
    for (int i = 0; i < 8; ++i) {
        const int c2 = t + i * 256;               // 0..2047: 128 rows x 16 f4
        const int rowLocal = c2 >> 4;
        const int q = c2 & 15;
        const int codeB = bestL[rowLocal];
        const float4 v = emb4[codeB * 16 + q];
        const long long o = (blockRow + rowLocal) * 16 + q;
        out4[o] = v;
        out4[o + total4] = v;
    }
}

// ===========================================================================
// Kernel C: numpy-bit-exact re-resolution of flagged rows; writes out
// directly (both copies). launch_bounds(256,1): za/eb stay in registers.
// ===========================================================================
__global__ __launch_bounds__(256, 1) void vq_refine_np_kernel(
    const float* __restrict__ z, const float* __restrict__ emb,
    const float* __restrict__ ee, const int* __restrict__ wl,
    const int* __restrict__ wl_cnt, float* __restrict__ out, long long nRows)
{
    const int lane = threadIdx.x & 63;
    const int wid  = blockIdx.x * 4 + (threadIdx.x >> 6);
    const int nW   = gridDim.x * 4;
    const int cnt  = min(*wl_cnt, WL_CAP);
    const long long totalF = nRows * 64;

    for (int i = wid; i < cnt; i += nW) {
        const long long r = wl[i];

        float za[64];
        const float4* z4 = reinterpret_cast<const float4*>(z + r * D);
        #pragma unroll
        for (int j = 0; j < 16; ++j) {
            float4 tt = z4[j];
            za[4*j] = tt.x; za[4*j+1] = tt.y; za[4*j+2] = tt.z; za[4*j+3] = tt.w;
        }
        const float zz = np_pairwise64_sq(za);

        float best = FLT_MAX; int bk = 0x7fffffff;
        for (int i8 = 0; i8 < 8; ++i8) {
            const int k = (i8 << 6) + lane;          // ascending per lane
            float eb[64];
            const float4* e4 = reinterpret_cast<const float4*>(emb) + k * 16;
            #pragma unroll
            for (int j = 0; j < 16; ++j) {
                float4 tt = e4[j];
                eb[4*j] = tt.x; eb[4*j+1] = tt.y; eb[4*j+2] = tt.z; eb[4*j+3] = tt.w;
            }
            const float G = np_seqfma_dot64(za, eb);
            const float dist = __fadd_rn(__fsub_rn(zz, __fmul_rn(2.0f, G)), ee[k]);
            if (dist < best) { best = dist; bk = k; }
        }
        // cross-lane min, lowest-k tie-break (== numpy first-min)
        #pragma unroll
        for (int off = 32; off; off >>= 1) {
            const float ob = __shfl_xor(best, off);
            const int   ok = __shfl_xor(bk, off);
            if (ob < best || (ob == best && ok < bk)) { best = ob; bk = ok; }
        }
        // patch both output copies (256B each, 1 float/lane)
        const float v = emb[bk * D + lane];
        out[r * D + lane] = v;
        out[totalF + r * D + lane] = v;
    }
}

// ===========================================================================
extern "C" void kernel_launch(void* const* d_in, const int* in_sizes, int n_in,
                              void* d_out, int out_size, void* d_ws, size_t ws_size,
                              hipStream_t stream) {
    const float* z   = (const float*)d_in[0];   // [N, 64] fp32
    const float* emb = (const float*)d_in[1];   // [512, 64] fp32
    float* out = (float*)d_out;                 // 2 x [N, 64] fp32

    const long long nRows = (long long)in_sizes[0] / D;       // 524288

    char* p = (char*)d_ws;
    float* ee     = (float*)p;                        // 2 KB
    short* ehl    = (short*)(p + 4096);               // 128 KB
    int*   wl_cnt = (int*)(p + 4096 + 131072);        // 4 B (pad to 256)
    int*   wl     = (int*)(p + 4096 + 131072 + 256);  // 1 MB

    vq_prep_kernel<<<32, 256, 0, stream>>>(emb, ehl, ee, wl_cnt);

    const int scoreBlocks = (int)(nRows / 128);               // 4096
    vq_score_fused_kernel<<<scoreBlocks, 256, 0, stream>>>(
        z, ehl, ee, emb, out, wl, wl_cnt, nRows);

    vq_refine_np_kernel<<<512, 256, 0, stream>>>(z, emb, ee, wl, wl_cnt, out, nRows);
}

// Round 12
// 497.687 us; speedup vs baseline: 2.0268x; 1.2810x over previous
//
#include <hip/hip_runtime.h>
#include <cfloat>

#define D 64
#define K 512
#define MARGIN 4e-4f
#define CAP1 262144
#define CAP2 65536

typedef __attribute__((ext_vector_type(8))) short bf16x8;
typedef __attribute__((ext_vector_type(4))) float f32x4;

__device__ __forceinline__ short f2bf(float x) {          // fp32 -> bf16 RNE
    unsigned u = __float_as_uint(x);
    u += 0x7fffu + ((u >> 16) & 1u);
    return (short)(u >> 16);
}
__device__ __forceinline__ float bf2f(short s) {
    return __uint_as_float(((unsigned)(unsigned short)s) << 16);
}

// ===========================================================================
// numpy-bit-exact helpers (VERIFIED bit-match R3-R10: absmax 0.0)
// ===========================================================================
__device__ __forceinline__ float np_pairwise64_sq(const float* a) {
    float r[8];
    #pragma unroll
    for (int j = 0; j < 8; ++j) r[j] = __fmul_rn(a[j], a[j]);
    #pragma unroll
    for (int i = 8; i < 64; i += 8) {
        #pragma unroll
        for (int j = 0; j < 8; ++j)
            r[j] = __fadd_rn(r[j], __fmul_rn(a[i + j], a[i + j]));
    }
    return __fadd_rn(__fadd_rn(__fadd_rn(r[0], r[1]), __fadd_rn(r[2], r[3])),
                     __fadd_rn(__fadd_rn(r[4], r[5]), __fadd_rn(r[6], r[7])));
}

// BLAS seq-FMA dot, d ascending (VERIFIED ref cross-term order)
__device__ __forceinline__ float np_seqfma_dot64(const float* x, const float* y) {
    float acc = 0.f;
    #pragma unroll
    for (int d = 0; d < 64; ++d) acc = __fmaf_rn(x[d], y[d], acc);
    return acc;
}

// ===========================================================================
// Kernel P: one-time prep.
//  - ehl: bf16 hi/lo split of E, fragment row = (ch*32 + ctf*4 + p), each
//    row 512 shorts (64 lanes x 8). ch=code>>7, ctf=(code>>4)&7, p=part.
//  - embT[64][512]: transpose of emb (coalesced full-scan refine)
//  - ee (np-exact), eeq = fl(ee + 0.5)
//  - zero both worklist counters
// ===========================================================================
__global__ void vq_prep_kernel(const float* __restrict__ emb, short* __restrict__ ehl,
                               float* __restrict__ embT, float* __restrict__ ee,
                               float* __restrict__ eeq, int* __restrict__ cnts) {
    const int t = threadIdx.x, b = blockIdx.x;
    if (b == 0 && t < 2) cnts[t] = 0;

    const int gid = b * 256 + t;                      // 8192 jobs
    // --- ehl fragments
    {
        const int l  = gid & 63;
        const int p  = (gid >> 6) & 3;
        const int code = ((gid >> 11) << 7) + (((gid >> 8) & 7) << 4) + (l & 15);
        const int d0 = ((p & 1) << 5) + ((l >> 4) << 3);
        const float4 v0 = *(const float4*)(emb + code * D + d0);
        const float4 v1 = *(const float4*)(emb + code * D + d0 + 4);
        const float f[8] = {v0.x, v0.y, v0.z, v0.w, v1.x, v1.y, v1.z, v1.w};
        bf16x8 o;
        #pragma unroll
        for (int j = 0; j < 8; ++j) {
            const short h = f2bf(f[j]);
            o[j] = (p < 2) ? h : f2bf(f[j] - bf2f(h));
        }
        *(bf16x8*)(ehl + (long long)gid * 8) = o;
    }
    // --- embT: d = gid>>7, k-base = (gid&127)*4
    {
        const int d  = gid >> 7;
        const int kb = (gid & 127) << 2;
        float4 v;
        v.x = emb[(kb + 0) * D + d];
        v.y = emb[(kb + 1) * D + d];
        v.z = emb[(kb + 2) * D + d];
        v.w = emb[(kb + 3) * D + d];
        *(float4*)(embT + d * 512 + kb) = v;
    }
    // --- ee / eeq
    if (b < 2) {
        const int k = b * 256 + t;
        float e[64];
        const float4* e4 = reinterpret_cast<const float4*>(emb) + k * 16;
        #pragma unroll
        for (int j = 0; j < 16; ++j) {
            float4 tt = e4[j];
            e[4*j] = tt.x; e[4*j+1] = tt.y; e[4*j+2] = tt.z; e[4*j+3] = tt.w;
        }
        const float s = np_pairwise64_sq(e);
        ee[k]  = s;
        eeq[k] = s + 0.5f;
    }
}

// ===========================================================================
// Kernel A: barrier-light MFMA score + fused z_q write.
// 256 thr = 4 independent waves; wave owns 32 rows (2 A-tiles), streams all
// 512 codes reading B fragments DIRECTLY from L2-resident ehl (no LDS
// staging; one __syncthreads total, before the gather). Fast-path numerics
// identical to verified R9/R10 PASS. Tracks packed top-3:
//   pair-ambiguous (f2-f1<M<=f3-f1): ref-argmin provably in {k1,k2} -> wl1
//   3-way ambiguous (f3-f1<M): full exact rescan -> wl2
// FRAGMENT ADDR (R11 bug fixed): row base for (hc,ct) = hc*16 + ct*4.
// ===========================================================================
__global__ __launch_bounds__(256, 4) void vq_score_kernel(
    const float* __restrict__ z, const short* __restrict__ ehl,
    const float* __restrict__ eeq, const float* __restrict__ emb,
    float* __restrict__ out, int2* __restrict__ wl1, int* __restrict__ wl2,
    int* __restrict__ cnts, long long nRows)
{
    __shared__ int bestW[4][32];      // per-wave result handoff

    const int t  = threadIdx.x;
    const int l  = t & 63;
    const int w  = t >> 6;
    const int kg = l >> 4;
    const int cl = l & 15;

    const long long wrow = (long long)blockIdx.x * 128 + w * 32;

    // ---- A fragments: 2 tiles x (hi d0-31, hi d32-63, lo d0-31, lo d32-63)
    bf16x8 aH0[2], aH1[2], aL0[2], aL1[2];
    #pragma unroll
    for (int a = 0; a < 2; ++a) {
        const float* zr = z + (wrow + a * 16 + cl) * D;
        const float4 v0 = *(const float4*)(zr + kg * 8);
        const float4 v1 = *(const float4*)(zr + kg * 8 + 4);
        const float4 v2 = *(const float4*)(zr + 32 + kg * 8);
        const float4 v3 = *(const float4*)(zr + 32 + kg * 8 + 4);
        const float d0[8] = {v0.x,v0.y,v0.z,v0.w,v1.x,v1.y,v1.z,v1.w};
        const float d1[8] = {v2.x,v2.y,v2.z,v2.w,v3.x,v3.y,v3.z,v3.w};
        #pragma unroll
        for (int i = 0; i < 8; ++i) {
            const short h = f2bf(d0[i]); aH0[a][i] = h; aL0[a][i] = f2bf(d0[i] - bf2f(h));
            const short g = f2bf(d1[i]); aH1[a][i] = g; aL1[a][i] = f2bf(d1[i] - bf2f(g));
        }
    }

    unsigned m1[2][4], m2[2][4], m3[2][4];
    #pragma unroll
    for (int a = 0; a < 2; ++a)
        #pragma unroll
        for (int r = 0; r < 4; ++r) {
            m1[a][r] = 0x7f800000u; m2[a][r] = 0x7f800000u; m3[a][r] = 0x7f800000u;
        }

    #pragma unroll 2
    for (int hc = 0; hc < 8; ++hc) {
        #pragma unroll
        for (int ct = 0; ct < 4; ++ct) {
            // fragment rows (hc*16 + ct*4 + p), p = 0..3   [R11 bug: hc*32]
            const short* fb = ehl + (hc * 16 + ct * 4) * 512 + l * 8;
            const bf16x8 b0 = *(const bf16x8*)(fb);
            const bf16x8 b1 = *(const bf16x8*)(fb + 512);
            const bf16x8 b2 = *(const bf16x8*)(fb + 1024);
            const bf16x8 b3 = *(const bf16x8*)(fb + 1536);
            const float ek05 = eeq[hc * 64 + ct * 16 + cl];

            f32x4 acc0 = {0.f, 0.f, 0.f, 0.f};
            f32x4 acc1 = {0.f, 0.f, 0.f, 0.f};
            acc0 = __builtin_amdgcn_mfma_f32_16x16x32_bf16(aH0[0], b0, acc0, 0, 0, 0);
            acc1 = __builtin_amdgcn_mfma_f32_16x16x32_bf16(aH0[1], b0, acc1, 0, 0, 0);
            acc0 = __builtin_amdgcn_mfma_f32_16x16x32_bf16(aH1[0], b1, acc0, 0, 0, 0);
            acc1 = __builtin_amdgcn_mfma_f32_16x16x32_bf16(aH1[1], b1, acc1, 0, 0, 0);
            acc0 = __builtin_amdgcn_mfma_f32_16x16x32_bf16(aH0[0], b2, acc0, 0, 0, 0);
            acc1 = __builtin_amdgcn_mfma_f32_16x16x32_bf16(aH0[1], b2, acc1, 0, 0, 0);
            acc0 = __builtin_amdgcn_mfma_f32_16x16x32_bf16(aH1[0], b3, acc0, 0, 0, 0);
            acc1 = __builtin_amdgcn_mfma_f32_16x16x32_bf16(aH1[1], b3, acc1, 0, 0, 0);
            acc0 = __builtin_amdgcn_mfma_f32_16x16x32_bf16(aL0[0], b0, acc0, 0, 0, 0);
            acc1 = __builtin_amdgcn_mfma_f32_16x16x32_bf16(aL0[1], b0, acc1, 0, 0, 0);
            acc0 = __builtin_amdgcn_mfma_f32_16x16x32_bf16(aL1[0], b1, acc0, 0, 0, 0);
            acc1 = __builtin_amdgcn_mfma_f32_16x16x32_bf16(aL1[1], b1, acc1, 0, 0, 0);

            const unsigned code = (unsigned)((hc * 64 + ct * 16) | cl);
            #pragma unroll
            for (int r = 0; r < 4; ++r) {
                const float s0 = __fmaf_rn(-2.0f, acc0[r], ek05);   // > 0 always
                const unsigned p0 = (__float_as_uint(s0) & 0xfffffe00u) | code;
                unsigned t2 = max(m1[0][r], p0); m1[0][r] = min(m1[0][r], p0);
                unsigned t3 = max(m2[0][r], t2); m2[0][r] = min(m2[0][r], t2);
                m3[0][r] = min(m3[0][r], t3);
                const float s1 = __fmaf_rn(-2.0f, acc1[r], ek05);
                const unsigned p1 = (__float_as_uint(s1) & 0xfffffe00u) | code;
                t2 = max(m1[1][r], p1); m1[1][r] = min(m1[1][r], p1);
                t3 = max(m2[1][r], t2); m2[1][r] = min(m2[1][r], t2);
                m3[1][r] = min(m3[1][r], t3);
            }
        }
    }

    // merge sorted triples across the 16 cl-lanes of each kg group
    #pragma unroll
    for (int a = 0; a < 2; ++a) {
        #pragma unroll
        for (int r = 0; r < 4; ++r) {
            #pragma unroll
            for (int off = 1; off < 16; off <<= 1) {
                const unsigned b1v = (unsigned)__shfl_xor((int)m1[a][r], off);
                const unsigned b2v = (unsigned)__shfl_xor((int)m2[a][r], off);
                const unsigned b3v = (unsigned)__shfl_xor((int)m3[a][r], off);
                const unsigned a1v = m1[a][r], a2v = m2[a][r], a3v = m3[a][r];
                m1[a][r] = min(a1v, b1v);
                m2[a][r] = min(max(a1v, b1v), min(a2v, b2v));
                m3[a][r] = min(min(max(a2v, b1v), max(a1v, b2v)), min(a3v, b3v));
            }
        }
    }

    // per-row results -> LDS + worklists (cl==0 lanes only)
    if (cl == 0) {
        #pragma unroll
        for (int a = 0; a < 2; ++a)
            #pragma unroll
            for (int r = 0; r < 4; ++r) {
                const int rowL = a * 16 + kg * 4 + r;     // D-row map (HW-verified)
                const int k1 = (int)(m1[a][r] & 511u);
                bestW[w][rowL] = k1;
                const float f1 = __uint_as_float(m1[a][r] & 0xfffffe00u);
                const float f2 = __uint_as_float(m2[a][r] & 0xfffffe00u);
                const float f3 = __uint_as_float(m3[a][r] & 0xfffffe00u);
                const int row = (int)(wrow + rowL);
                if (f3 - f1 < MARGIN) {                    // 3-way ambiguous
                    const int pos = atomicAdd(&cnts[1], 1);
                    if (pos < CAP2) wl2[pos] = row;
                } else if (f2 - f1 < MARGIN) {             // pair-ambiguous
                    const int k2 = (int)(m2[a][r] & 511u);
                    const int pos = atomicAdd(&cnts[0], 1);
                    if (pos < CAP1) wl1[pos] = make_int2(row, k1 | (k2 << 9));
                }
            }
    }
    __syncthreads();    // single barrier: bestW visible to all lanes

    // fused gather: this wave writes its own 32 rows, both tuple outputs
    const float4* emb4 = reinterpret_cast<const float4*>(emb);
    float4* out4 = reinterpret_cast<float4*>(out);
    const long long total4 = nRows * 16;
    #pragma unroll
    for (int i = 0; i < 8; ++i) {
        const int c2 = l + i * 64;                 // 0..511: 32 rows x 16 f4
        const int rowL = c2 >> 4;
        const int q = c2 & 15;
        const int code = bestW[w][rowL];
        const float4 v = emb4[code * 16 + q];
        const long long o = (wrow + rowL) * 16 + q;
        out4[o] = v;
        out4[o + total4] = v;
    }
}

// ===========================================================================
// Kernel R1: exact pair resolution. One lane per pair-ambiguous row; wave-
// uniform windows (base + m*nT), lane handles base+lane. Rewrites rows
// where the ref-exact winner differs from the fast choice k1.
// ===========================================================================
__global__ __launch_bounds__(256, 1) void vq_pair_kernel(
    const float* __restrict__ z, const float* __restrict__ emb,
    const float* __restrict__ ee, const int2* __restrict__ wl1,
    const int* __restrict__ cnts, float* __restrict__ out, long long nRows)
{
    const int lane = threadIdx.x & 63;
    const int nT   = gridDim.x * 256;
    const int waveBase0 = blockIdx.x * 256 + (threadIdx.x & ~63);
    const int cnt  = min(cnts[0], CAP1);
    const long long totalF = nRows * 64;

    for (int base = waveBase0; base < cnt; base += nT) {
        const int idx = base + lane;
        int row = 0, k1 = 0, winner = 0;
        const bool active = (idx < cnt);
        if (active) {
            const int2 e = wl1[idx];
            row = e.x; k1 = e.y & 511;
            const int k2 = (e.y >> 9) & 511;

            float za[64];
            const float4* z4 = reinterpret_cast<const float4*>(z + (long long)row * D);
            #pragma unroll
            for (int j = 0; j < 16; ++j) {
                float4 tt = z4[j];
                za[4*j] = tt.x; za[4*j+1] = tt.y; za[4*j+2] = tt.z; za[4*j+3] = tt.w;
            }
            const float zz = np_pairwise64_sq(za);

            float e1[64], e2[64];
            const float4* p1 = reinterpret_cast<const float4*>(emb + k1 * D);
            const float4* p2 = reinterpret_cast<const float4*>(emb + k2 * D);
            #pragma unroll
            for (int j = 0; j < 16; ++j) {
                float4 a = p1[j], b = p2[j];
                e1[4*j] = a.x; e1[4*j+1] = a.y; e1[4*j+2] = a.z; e1[4*j+3] = a.w;
                e2[4*j] = b.x; e2[4*j+1] = b.y; e2[4*j+2] = b.z; e2[4*j+3] = b.w;
            }
            const float G1 = np_seqfma_dot64(za, e1);
            const float G2 = np_seqfma_dot64(za, e2);
            const float d1 = __fadd_rn(__fsub_rn(zz, __fmul_rn(2.0f, G1)), ee[k1]);
            const float d2 = __fadd_rn(__fsub_rn(zz, __fmul_rn(2.0f, G2)), ee[k2]);
            winner = (d2 < d1) ? k2 : ((d1 < d2) ? k1 : min(k1, k2));
        }
        // coalesced rewrite of rows whose winner != fast choice
        unsigned long long mask = __ballot(active && (winner != k1));
        while (mask) {
            const int bit = __ffsll(mask) - 1;
            mask &= mask - 1;
            const int rb = __shfl(row, bit);
            const int wb = __shfl(winner, bit);
            const float v = emb[wb * D + lane];
            out[(long long)rb * D + lane] = v;
            out[totalF + (long long)rb * D + lane] = v;
        }
    }
}

// ===========================================================================
// Kernel R2: exact full-scan for 3-way-ambiguous rows (rare). One wave/row;
// lane owns codes g*64+lane (g asc); coalesced embT reads; np-bit exact.
// ===========================================================================
__global__ __launch_bounds__(256, 1) void vq_full_kernel(
    const float* __restrict__ z, const float* __restrict__ emb,
    const float* __restrict__ embT, const float* __restrict__ ee,
    const int* __restrict__ wl2, const int* __restrict__ cnts,
    float* __restrict__ out, long long nRows)
{
    const int lane = threadIdx.x & 63;
    const int wid  = blockIdx.x * 4 + (threadIdx.x >> 6);
    const int nW   = gridDim.x * 4;
    const int cnt  = min(cnts[1], CAP2);
    const long long totalF = nRows * 64;

    for (int i = wid; i < cnt; i += nW) {
        const int row = wl2[i];

        float za[64];
        const float4* z4 = reinterpret_cast<const float4*>(z + (long long)row * D);
        #pragma unroll
        for (int j = 0; j < 16; ++j) {
            float4 tt = z4[j];
            za[4*j] = tt.x; za[4*j+1] = tt.y; za[4*j+2] = tt.z; za[4*j+3] = tt.w;
        }
        const float zz = np_pairwise64_sq(za);

        float acc[8] = {0.f,0.f,0.f,0.f,0.f,0.f,0.f,0.f};
        for (int d = 0; d < 64; ++d) {
            const float zd = za[d];
            const float* ep = embT + d * 512 + lane;
            #pragma unroll
            for (int g = 0; g < 8; ++g)
                acc[g] = __fmaf_rn(zd, ep[g * 64], acc[g]);   // exact seq order in d
        }
        float best = FLT_MAX; int bk = 0x7fffffff;
        #pragma unroll
        for (int g = 0; g < 8; ++g) {
            const int k = g * 64 + lane;
            const float dist = __fadd_rn(__fsub_rn(zz, __fmul_rn(2.0f, acc[g])), ee[k]);
            if (dist < best) { best = dist; bk = k; }        // strict < : lowest g
        }
        #pragma unroll
        for (int off = 32; off; off >>= 1) {
            const float ob = __shfl_xor(best, off);
            const int   ok = __shfl_xor(bk, off);
            if (ob < best || (ob == best && ok < bk)) { best = ob; bk = ok; }
        }
        const float v = emb[bk * D + lane];
        out[(long long)row * D + lane] = v;
        out[totalF + (long long)row * D + lane] = v;
    }
}

// ===========================================================================
extern "C" void kernel_launch(void* const* d_in, const int* in_sizes, int n_in,
                              void* d_out, int out_size, void* d_ws, size_t ws_size,
                              hipStream_t stream) {
    const float* z   = (const float*)d_in[0];   // [N, 64] fp32
    const float* emb = (const float*)d_in[1];   // [512, 64] fp32
    float* out = (float*)d_out;                 // 2 x [N, 64] fp32

    const long long nRows = (long long)in_sizes[0] / D;       // 524288

    char* p = (char*)d_ws;
    float* ee   = (float*)p;                          // 2 KB
    float* eeq  = (float*)(p + 2048);                 // 2 KB
    short* ehl  = (short*)(p + 4096);                 // 128 KB
    float* embT = (float*)(p + 4096 + 131072);        // 128 KB
    int*   cnts = (int*)(p + 4096 + 262144);          // 8 B (pad 256)
    int2*  wl1  = (int2*)(p + 4096 + 262144 + 256);   // 2 MB
    int*   wl2  = (int*)(p + 4096 + 262144 + 256 + CAP1 * 8);  // 256 KB

    vq_prep_kernel<<<32, 256, 0, stream>>>(emb, ehl, embT, ee, eeq, cnts);

    const int scoreBlocks = (int)(nRows / 128);               // 4096
    vq_score_kernel<<<scoreBlocks, 256, 0, stream>>>(
        z, ehl, eeq, emb, out, wl1, wl2, cnts, nRows);

    vq_pair_kernel<<<256, 256, 0, stream>>>(z, emb, ee, wl1, cnts, out, nRows);
    vq_full_kernel<<<256, 256, 0, stream>>>(z, emb, embT, ee, wl2, cnts, out, nRows);
}